// Round 7
// baseline (337.771 us; speedup 1.0000x reference)
//
#include <hip/hip_runtime.h>
#include <hip/hip_bf16.h>

#define N_NODES 100000
#define N_EDGES 600000
#define FEAT 128
#define NUM_RELS 8
#define NUM_BASES 4
#define NBE 2344    // ceil(N_EDGES/256)

// grid partition for k_prep
#define PREP_CAST 6250                   // cast_h blocks (6250*256*8 = 12.8M bf16)
#define PREP_BLDB 320                    // build_b blocks (320*256 = 81920 = 5*128*128)
#define PREP_ZERO 391                    // cnt zero blocks
#define PREP_GRID (PREP_CAST + PREP_BLDB + PREP_ZERO)

typedef short bf16x8 __attribute__((ext_vector_type(8)));
typedef float f32x4  __attribute__((ext_vector_type(4)));
typedef float f32x2  __attribute__((ext_vector_type(2)));

__device__ inline short f2bf(float x) {
    __hip_bfloat16 b = __float2bfloat16(x);
    return *reinterpret_cast<short*>(&b);
}
__device__ inline float bfbits2f(unsigned int u16) {
    return __int_as_float(u16 << 16);
}

// ws layout (bytes):
//   hb    bf16[N*128]        @ 0            25,600,000
//   Bt    bf16[5*128*128]    @ 25,600,000   163,840   ([kc][o][i'] transposed)
//   z     bf16[N*512]        @ 25,763,840   102,400,000  ([d][b*128+i])
//   srcs  int[E]             @ 128,163,840  2,400,000 (dst-sorted src)
//   coef  float4[E]          @ 130,563,840  9,600,000 (dst-sorted w_comp[rel])
//   cnt   int[N]             @ 140,163,840  400,000
//   offs  int[N+1 pad]       @ 140,563,840  400,128
//   cursor int[N]            @ 140,963,968  400,000
// total ~141.4 MB

// ---------- k_prep: cast h->bf16 | build B^T | zero cnt (grid-partitioned) ----------
__global__ __launch_bounds__(256) void k_prep(const float* __restrict__ h,
                                              const float* __restrict__ weight,
                                              const float* __restrict__ rw,
                                              short* __restrict__ hb,
                                              short* __restrict__ Bt,
                                              int* __restrict__ cnt) {
    int b = blockIdx.x;
    if (b < PREP_CAST) {
        int i = b * 256 + threadIdx.x;                 // < 1.6M exactly
        const float4* h4 = (const float4*)h;
        float4 v0 = h4[2 * i], v1 = h4[2 * i + 1];
        union { short s[8]; bf16x8 v; } u;
        u.s[0] = f2bf(v0.x); u.s[1] = f2bf(v0.y); u.s[2] = f2bf(v0.z); u.s[3] = f2bf(v0.w);
        u.s[4] = f2bf(v1.x); u.s[5] = f2bf(v1.y); u.s[6] = f2bf(v1.z); u.s[7] = f2bf(v1.w);
        ((bf16x8*)hb)[i] = u.v;
    } else if (b < PREP_CAST + PREP_BLDB) {
        int idx = (b - PREP_CAST) * 256 + threadIdx.x; // < 81920 exactly
        int kc = idx >> 14;
        int e  = idx & 16383;
        int o  = e >> 7, ip = e & 127;
        float v = (kc == 0) ? rw[ip * FEAT + o]
                            : weight[(kc - 1) * FEAT * FEAT + ip * FEAT + o];
        Bt[idx] = f2bf(v);                             // Bt[kc][o][ip]
    } else {
        int i = (b - PREP_CAST - PREP_BLDB) * 256 + threadIdx.x;
        if (i < N_NODES) cnt[i] = 0;
    }
}

// ---------- dst histogram ----------
__global__ __launch_bounds__(256) void k_hist_dst(const int* __restrict__ dst,
                                                  int* __restrict__ cnt) {
    int i = blockIdx.x * 256 + threadIdx.x;
    if (i < N_EDGES) atomicAdd(&cnt[dst[i]], 1);       // 100K bins, ~6/bin
}

// ---------- single-block exclusive scan over cnt[100000] -> offs, cursor ----------
// 4 elements/thread/iter (int4), 98 iters of 1024 elements.
__global__ __launch_bounds__(256) void k_scan(const int* __restrict__ cnt,
                                              int* __restrict__ offs,
                                              int* __restrict__ cursor) {
    __shared__ int wsum[4];
    __shared__ int btot_s;
    int lane = threadIdx.x & 63, wid = threadIdx.x >> 6;
    const int4* cnt4 = (const int4*)cnt;
    int4* offs4 = (int4*)offs;
    int4* cur4  = (int4*)cursor;
    int carry = 0;
    const int NIT = (N_NODES / 4 + 255) / 256;         // 98
    for (int c = 0; c < NIT; ++c) {
        int i4 = c * 256 + threadIdx.x;
        int4 v = (i4 < N_NODES / 4) ? cnt4[i4] : make_int4(0, 0, 0, 0);
        int s = v.x + v.y + v.z + v.w;
        int incl = s;
#pragma unroll
        for (int d = 1; d < 64; d <<= 1) {
            int t = __shfl_up(incl, d);
            if (lane >= d) incl += t;
        }
        __syncthreads();                               // prev-iter reads done
        if (lane == 63) wsum[wid] = incl;
        __syncthreads();
        if (threadIdx.x == 0) {
            int a = 0;
#pragma unroll
            for (int w = 0; w < 4; ++w) { int x = wsum[w]; wsum[w] = a; a += x; }
            btot_s = a;
        }
        __syncthreads();
        int base = incl - s + wsum[wid] + carry;
        if (i4 < N_NODES / 4) {
            int4 ex;
            ex.x = base;
            ex.y = base + v.x;
            ex.z = base + v.x + v.y;
            ex.w = base + v.x + v.y + v.z;
            offs4[i4] = ex;
            cur4[i4]  = ex;
        }
        carry += btot_s;
    }
    if (threadIdx.x == 0) offs[N_NODES] = carry;       // == N_EDGES
}

// ---------- scatter: dst-sorted (src, w_comp[rel]) ----------
__global__ __launch_bounds__(256) void k_scatter_sorted(const int* __restrict__ src,
                                                        const int* __restrict__ dst,
                                                        const int* __restrict__ rel,
                                                        const float* __restrict__ wc,
                                                        int* __restrict__ cursor,
                                                        int* __restrict__ srcs,
                                                        float4* __restrict__ coef) {
    int e = blockIdx.x * 256 + threadIdx.x;
    if (e < N_EDGES) {
        int p = atomicAdd(&cursor[dst[e]], 1);         // ~6-way contention
        srcs[p] = src[e];
        int r = rel[e] * NUM_BASES;
        coef[p] = make_float4(wc[r], wc[r + 1], wc[r + 2], wc[r + 3]);
    }
}

// ---------- edge phase: z[d][b][:] = sum_{e->d} w_comp[rel,b] * h[src]  (1 wave/dst) ----------
// Packed f32x2 accumulators -> v_pk_fma_f32 (halves FMA instruction count).
__global__ __launch_bounds__(256) void k_edge_z(const int* __restrict__ offs,
                                                const int* __restrict__ srcs,
                                                const float4* __restrict__ coef,
                                                const short* __restrict__ hb,
                                                unsigned int* __restrict__ z_u32) {
    int wid = threadIdx.x >> 6, lane = threadIdx.x & 63;
    int d = blockIdx.x * 4 + wid;
    if (d >= N_NODES) return;
    int s = offs[d], e = offs[d + 1];

    f32x2 z2[4] = {(f32x2)0.f, (f32x2)0.f, (f32x2)0.f, (f32x2)0.f};

    int i = s;
    for (; i + 1 < e; i += 2) {                        // 2-deep for load ILP
        int s0 = srcs[i], s1 = srcs[i + 1];
        float4 c0 = coef[i], c1 = coef[i + 1];
        unsigned int v0 = ((const unsigned int*)(hb + (size_t)s0 * FEAT))[lane];
        unsigned int v1 = ((const unsigned int*)(hb + (size_t)s1 * FEAT))[lane];
        f32x2 h0; h0.x = bfbits2f(v0 & 0xffffu); h0.y = bfbits2f(v0 >> 16);
        f32x2 h1; h1.x = bfbits2f(v1 & 0xffffu); h1.y = bfbits2f(v1 >> 16);
        f32x2 cc;
        cc = c0.x; z2[0] += cc * h0;
        cc = c0.y; z2[1] += cc * h0;
        cc = c0.z; z2[2] += cc * h0;
        cc = c0.w; z2[3] += cc * h0;
        cc = c1.x; z2[0] += cc * h1;
        cc = c1.y; z2[1] += cc * h1;
        cc = c1.z; z2[2] += cc * h1;
        cc = c1.w; z2[3] += cc * h1;
    }
    if (i < e) {
        int s0 = srcs[i];
        float4 c0 = coef[i];
        unsigned int v0 = ((const unsigned int*)(hb + (size_t)s0 * FEAT))[lane];
        f32x2 h0; h0.x = bfbits2f(v0 & 0xffffu); h0.y = bfbits2f(v0 >> 16);
        f32x2 cc;
        cc = c0.x; z2[0] += cc * h0;
        cc = c0.y; z2[1] += cc * h0;
        cc = c0.z; z2[2] += cc * h0;
        cc = c0.w; z2[3] += cc * h0;
    }

    unsigned int* row = z_u32 + (size_t)d * 256;       // 512 bf16 = 256 u32
#pragma unroll
    for (int b = 0; b < 4; ++b) {
        unsigned int lo = ((unsigned int)(unsigned short)f2bf(z2[b].x));
        unsigned int hi = ((unsigned int)(unsigned short)f2bf(z2[b].y)) << 16;
        row[b * 64 + lane] = lo | hi;                  // coalesced 256B per b
    }
}

// ---------- fused GEMM: out = relu([hb | z] @ Bt + bias), K=640 ----------
// B-fragment: lane n16 owns 8 consecutive out cols o=8*n16+nt.
// LDS swizzle: chunk c of row o stored at (o<<4) + ((c + (o>>3)) & 15).
__global__ __launch_bounds__(256) void k_gemm_fused(const short* __restrict__ hb,
                                                    const short* __restrict__ z,
                                                    const short* __restrict__ Bt,
                                                    const float* __restrict__ bias,
                                                    float* __restrict__ out) {
    __shared__ short lds[FEAT * FEAT];                  // 32 KB (one K-chunk of B^T)
    int wave = threadIdx.x >> 6, lane = threadIdx.x & 63;
    int quad = lane >> 4, n16 = lane & 15;
    int base = blockIdx.x * 128 + wave * 32;

    int rowA0 = base + n16;        if (rowA0 >= N_NODES) rowA0 = N_NODES - 1;
    int rowA1 = base + 16 + n16;   if (rowA1 >= N_NODES) rowA1 = N_NODES - 1;

    f32x4 acc[2][8];
#pragma unroll
    for (int mt = 0; mt < 2; ++mt)
#pragma unroll
        for (int nt = 0; nt < 8; ++nt) acc[mt][nt] = (f32x4)0.f;

    float4* l4 = (float4*)lds;
    const bf16x8* bp = (const bf16x8*)lds;

    for (int kc = 0; kc < 5; ++kc) {
        if (kc) __syncthreads();                        // drain reads before restage
        const float4* s4 = (const float4*)(Bt + kc * FEAT * FEAT);
#pragma unroll
        for (int t = 0; t < 8; ++t) {
            int linear = threadIdx.x + t * 256;
            int o = linear >> 4, c = linear & 15;
            l4[(o << 4) + ((c + (o >> 3)) & 15)] = s4[linear];
        }
        __syncthreads();

        const bf16x8* a0p = (kc == 0)
            ? (const bf16x8*)(hb + (size_t)rowA0 * FEAT)
            : (const bf16x8*)(z + (size_t)rowA0 * 512 + (kc - 1) * FEAT);
        const bf16x8* a1p = (kc == 0)
            ? (const bf16x8*)(hb + (size_t)rowA1 * FEAT)
            : (const bf16x8*)(z + (size_t)rowA1 * 512 + (kc - 1) * FEAT);

#pragma unroll
        for (int ks = 0; ks < 4; ++ks) {
            bf16x8 a0 = a0p[ks * 4 + quad];
            bf16x8 a1 = a1p[ks * 4 + quad];
            int sw = (ks * 4 + quad + n16) & 15;
#pragma unroll
            for (int nt = 0; nt < 8; ++nt) {
                int o = n16 * 8 + nt;
                bf16x8 b = bp[(o << 4) + sw];
                acc[0][nt] = __builtin_amdgcn_mfma_f32_16x16x32_bf16(a0, b, acc[0][nt], 0, 0, 0);
                acc[1][nt] = __builtin_amdgcn_mfma_f32_16x16x32_bf16(a1, b, acc[1][nt], 0, 0, 0);
            }
        }
    }

    float bv[8];
#pragma unroll
    for (int nt = 0; nt < 8; ++nt) bv[nt] = bias[n16 * 8 + nt];

#pragma unroll
    for (int mt = 0; mt < 2; ++mt)
#pragma unroll
        for (int reg = 0; reg < 4; ++reg) {
            int node = base + mt * 16 + quad * 4 + reg;
            if (node < N_NODES) {
                float4 fa, fb;
                fa.x = fmaxf(acc[mt][0][reg] + bv[0], 0.f);
                fa.y = fmaxf(acc[mt][1][reg] + bv[1], 0.f);
                fa.z = fmaxf(acc[mt][2][reg] + bv[2], 0.f);
                fa.w = fmaxf(acc[mt][3][reg] + bv[3], 0.f);
                fb.x = fmaxf(acc[mt][4][reg] + bv[4], 0.f);
                fb.y = fmaxf(acc[mt][5][reg] + bv[5], 0.f);
                fb.z = fmaxf(acc[mt][6][reg] + bv[6], 0.f);
                fb.w = fmaxf(acc[mt][7][reg] + bv[7], 0.f);
                float* row = out + (size_t)node * FEAT + n16 * 8;
                *(float4*)row       = fa;
                *(float4*)(row + 4) = fb;
            }
        }
}

// ============================ launch ============================

extern "C" void kernel_launch(void* const* d_in, const int* in_sizes, int n_in,
                              void* d_out, int out_size, void* d_ws, size_t ws_size,
                              hipStream_t stream) {
    const float* h    = (const float*)d_in[0];
    const float* wgt  = (const float*)d_in[1];
    const float* wcmp = (const float*)d_in[2];
    const float* rw   = (const float*)d_in[3];
    const float* bias = (const float*)d_in[4];
    const int*   src  = (const int*)d_in[5];
    const int*   dst  = (const int*)d_in[6];
    const int*   rel  = (const int*)d_in[7];
    float* out = (float*)d_out;

    char* ws = (char*)d_ws;
    short*        hb     = (short*)(ws + 0);
    short*        Bt     = (short*)(ws + 25600000ull);
    short*        z      = (short*)(ws + 25763840ull);
    unsigned int* z_u32  = (unsigned int*)z;
    int*          srcs   = (int*)(ws + 128163840ull);
    float4*       coef   = (float4*)(ws + 130563840ull);
    int*          cnt    = (int*)(ws + 140163840ull);
    int*          offs   = (int*)(ws + 140563840ull);
    int*          cursor = (int*)(ws + 140963968ull);

    hipLaunchKernelGGL(k_prep,     dim3(PREP_GRID), dim3(256), 0, stream,
                       h, wgt, rw, hb, Bt, cnt);
    hipLaunchKernelGGL(k_hist_dst, dim3(NBE),  dim3(256), 0, stream, dst, cnt);
    hipLaunchKernelGGL(k_scan,     dim3(1),    dim3(256), 0, stream, cnt, offs, cursor);
    hipLaunchKernelGGL(k_scatter_sorted, dim3(NBE), dim3(256), 0, stream,
                       src, dst, rel, wcmp, cursor, srcs, coef);
    hipLaunchKernelGGL(k_edge_z,   dim3((N_NODES + 3) / 4), dim3(256), 0, stream,
                       offs, srcs, coef, hb, z_u32);
    hipLaunchKernelGGL(k_gemm_fused, dim3((N_NODES + 127) / 128), dim3(256), 0, stream,
                       hb, z, Bt, bias, out);
}

// Round 8
// 285.574 us; speedup vs baseline: 1.1828x; 1.1828x over previous
//
#include <hip/hip_runtime.h>
#include <hip/hip_bf16.h>

#define N_NODES 100000
#define N_EDGES 600000
#define FEAT 128
#define NUM_RELS 8
#define NUM_BASES 4
#define NBE 2344    // ceil(N_EDGES/256)

// grid partition for k_prep
#define PREP_CAST 6250                   // cast_h blocks (6250*256*8 = 12.8M bf16)
#define PREP_BLDB 320                    // build_b blocks (320*256 = 81920 = 5*128*128)
#define PREP_ZERO 392                    // cnt (100000) + scan status (128) zero blocks
#define PREP_GRID (PREP_CAST + PREP_BLDB + PREP_ZERO)

#define SCAN_TILES 98                    // ceil(25000 int4 / 256)

typedef short bf16x8 __attribute__((ext_vector_type(8)));
typedef float f32x4  __attribute__((ext_vector_type(4)));
typedef float f32x2  __attribute__((ext_vector_type(2)));

__device__ inline short f2bf(float x) {
    __hip_bfloat16 b = __float2bfloat16(x);
    return *reinterpret_cast<short*>(&b);
}
__device__ inline float bfbits2f(unsigned int u16) {
    return __int_as_float(u16 << 16);
}

// ws layout (bytes):
//   hb    bf16[N*128]        @ 0            25,600,000
//   Bt    bf16[5*128*128]    @ 25,600,000   163,840   ([kc][o][i'] transposed)
//   z     bf16[N*512]        @ 25,763,840   102,400,000  ([d][b*128+i])
//   srcs  int[E]             @ 128,163,840  2,400,000 (dst-sorted src)
//   coef  float4[E]          @ 130,563,840  9,600,000 (dst-sorted w_comp[rel])
//   cnt   int[N]             @ 140,163,840  400,000
//   offs  int[N+1 pad]       @ 140,563,840  400,128
//   cursor int[N]            @ 140,963,968  400,000
//   status int[128]          @ 141,363,968  512      (lookback-scan tile status)
// total ~141.4 MB

// ---------- k_prep: cast h->bf16 | build B^T | zero cnt+status (grid-partitioned) ----------
__global__ __launch_bounds__(256) void k_prep(const float* __restrict__ h,
                                              const float* __restrict__ weight,
                                              const float* __restrict__ rw,
                                              short* __restrict__ hb,
                                              short* __restrict__ Bt,
                                              int* __restrict__ cnt,
                                              int* __restrict__ status) {
    int b = blockIdx.x;
    if (b < PREP_CAST) {
        int i = b * 256 + threadIdx.x;                 // < 1.6M exactly
        const float4* h4 = (const float4*)h;
        float4 v0 = h4[2 * i], v1 = h4[2 * i + 1];
        union { short s[8]; bf16x8 v; } u;
        u.s[0] = f2bf(v0.x); u.s[1] = f2bf(v0.y); u.s[2] = f2bf(v0.z); u.s[3] = f2bf(v0.w);
        u.s[4] = f2bf(v1.x); u.s[5] = f2bf(v1.y); u.s[6] = f2bf(v1.z); u.s[7] = f2bf(v1.w);
        ((bf16x8*)hb)[i] = u.v;
    } else if (b < PREP_CAST + PREP_BLDB) {
        int idx = (b - PREP_CAST) * 256 + threadIdx.x; // < 81920 exactly
        int kc = idx >> 14;
        int e  = idx & 16383;
        int o  = e >> 7, ip = e & 127;
        float v = (kc == 0) ? rw[ip * FEAT + o]
                            : weight[(kc - 1) * FEAT * FEAT + ip * FEAT + o];
        Bt[idx] = f2bf(v);                             // Bt[kc][o][ip]
    } else {
        int i = (b - PREP_CAST - PREP_BLDB) * 256 + threadIdx.x;
        if (i < N_NODES) cnt[i] = 0;
        else if (i - N_NODES < 128) status[i - N_NODES] = 0;
    }
}

// ---------- dst histogram ----------
__global__ __launch_bounds__(256) void k_hist_dst(const int* __restrict__ dst,
                                                  int* __restrict__ cnt) {
    int i = blockIdx.x * 256 + threadIdx.x;
    if (i < N_EDGES) atomicAdd(&cnt[dst[i]], 1);       // 100K bins, ~6/bin
}

// ---------- decoupled-lookback exclusive scan over cnt[100000] -> offs, cursor ----------
// 98 tiles of 1024 ints (256 thr x int4). status word = (value<<2)|flag;
// flag 1 = aggregate ready, 2 = inclusive-prefix ready. Single-word device-scope
// atomics only (no cross-location ordering assumptions). All 98 blocks co-resident.
__global__ __launch_bounds__(256) void k_scan_lb(const int* __restrict__ cnt,
                                                 int* __restrict__ offs,
                                                 int* __restrict__ cursor,
                                                 int* __restrict__ status) {
    __shared__ int wsum[4];
    __shared__ int bcast;
    int bid = blockIdx.x;
    int lane = threadIdx.x & 63, wid = threadIdx.x >> 6;
    const int N4 = N_NODES / 4;                        // 25000
    int i4 = bid * 256 + threadIdx.x;

    const int4* cnt4 = (const int4*)cnt;
    int4 v = (i4 < N4) ? cnt4[i4] : make_int4(0, 0, 0, 0);
    int s = v.x + v.y + v.z + v.w;
    int incl = s;
#pragma unroll
    for (int d = 1; d < 64; d <<= 1) {
        int t = __shfl_up(incl, d);
        if (lane >= d) incl += t;
    }
    if (lane == 63) wsum[wid] = incl;
    __syncthreads();
    if (threadIdx.x == 0) {
        int a = 0;
#pragma unroll
        for (int w = 0; w < 4; ++w) { int x = wsum[w]; wsum[w] = a; a += x; }
        int total = a;
        // publish aggregate immediately so successors can make progress
        __hip_atomic_store(&status[bid], (total << 2) | 1,
                           __ATOMIC_RELEASE, __HIP_MEMORY_SCOPE_AGENT);
        int excl = 0;
        for (int t = bid - 1; t >= 0; ) {
            int st = __hip_atomic_load(&status[t],
                                       __ATOMIC_ACQUIRE, __HIP_MEMORY_SCOPE_AGENT);
            if ((st & 3) == 0) { __builtin_amdgcn_s_sleep(1); continue; }
            excl += st >> 2;
            if ((st & 3) == 2) break;
            --t;
        }
        __hip_atomic_store(&status[bid], ((excl + total) << 2) | 2,
                           __ATOMIC_RELEASE, __HIP_MEMORY_SCOPE_AGENT);
        bcast = excl;
        if (bid == SCAN_TILES - 1) offs[N_NODES] = excl + total;   // == N_EDGES
    }
    __syncthreads();
    int base = bcast + wsum[wid] + incl - s;
    if (i4 < N4) {
        int4 ex;
        ex.x = base;
        ex.y = base + v.x;
        ex.z = base + v.x + v.y;
        ex.w = base + v.x + v.y + v.z;
        ((int4*)offs)[i4]   = ex;
        ((int4*)cursor)[i4] = ex;
    }
}

// ---------- scatter: dst-sorted (src, w_comp[rel]) ----------
__global__ __launch_bounds__(256) void k_scatter_sorted(const int* __restrict__ src,
                                                        const int* __restrict__ dst,
                                                        const int* __restrict__ rel,
                                                        const float* __restrict__ wc,
                                                        int* __restrict__ cursor,
                                                        int* __restrict__ srcs,
                                                        float4* __restrict__ coef) {
    int e = blockIdx.x * 256 + threadIdx.x;
    if (e < N_EDGES) {
        int p = atomicAdd(&cursor[dst[e]], 1);         // ~6-way contention
        srcs[p] = src[e];
        int r = rel[e] * NUM_BASES;
        coef[p] = make_float4(wc[r], wc[r + 1], wc[r + 2], wc[r + 3]);
    }
}

// ---------- edge phase: z[d][b][:] = sum_{e->d} w_comp[rel,b] * h[src]  (1 wave/dst) ----------
__global__ __launch_bounds__(256) void k_edge_z(const int* __restrict__ offs,
                                                const int* __restrict__ srcs,
                                                const float4* __restrict__ coef,
                                                const short* __restrict__ hb,
                                                unsigned int* __restrict__ z_u32) {
    int wid = threadIdx.x >> 6, lane = threadIdx.x & 63;
    int d = blockIdx.x * 4 + wid;
    if (d >= N_NODES) return;
    int s = offs[d], e = offs[d + 1];

    f32x2 z2[4] = {(f32x2)0.f, (f32x2)0.f, (f32x2)0.f, (f32x2)0.f};

    int i = s;
    for (; i + 1 < e; i += 2) {                        // 2-deep for load ILP
        int s0 = srcs[i], s1 = srcs[i + 1];
        float4 c0 = coef[i], c1 = coef[i + 1];
        unsigned int v0 = ((const unsigned int*)(hb + (size_t)s0 * FEAT))[lane];
        unsigned int v1 = ((const unsigned int*)(hb + (size_t)s1 * FEAT))[lane];
        f32x2 h0; h0.x = bfbits2f(v0 & 0xffffu); h0.y = bfbits2f(v0 >> 16);
        f32x2 h1; h1.x = bfbits2f(v1 & 0xffffu); h1.y = bfbits2f(v1 >> 16);
        f32x2 cc;
        cc = c0.x; z2[0] += cc * h0;
        cc = c0.y; z2[1] += cc * h0;
        cc = c0.z; z2[2] += cc * h0;
        cc = c0.w; z2[3] += cc * h0;
        cc = c1.x; z2[0] += cc * h1;
        cc = c1.y; z2[1] += cc * h1;
        cc = c1.z; z2[2] += cc * h1;
        cc = c1.w; z2[3] += cc * h1;
    }
    if (i < e) {
        int s0 = srcs[i];
        float4 c0 = coef[i];
        unsigned int v0 = ((const unsigned int*)(hb + (size_t)s0 * FEAT))[lane];
        f32x2 h0; h0.x = bfbits2f(v0 & 0xffffu); h0.y = bfbits2f(v0 >> 16);
        f32x2 cc;
        cc = c0.x; z2[0] += cc * h0;
        cc = c0.y; z2[1] += cc * h0;
        cc = c0.z; z2[2] += cc * h0;
        cc = c0.w; z2[3] += cc * h0;
    }

    unsigned int* row = z_u32 + (size_t)d * 256;       // 512 bf16 = 256 u32
#pragma unroll
    for (int b = 0; b < 4; ++b) {
        unsigned int lo = ((unsigned int)(unsigned short)f2bf(z2[b].x));
        unsigned int hi = ((unsigned int)(unsigned short)f2bf(z2[b].y)) << 16;
        row[b * 64 + lane] = lo | hi;                  // coalesced 256B per b
    }
}

// ---------- fused GEMM: out = relu([hb | z] @ Bt + bias), K=640 ----------
// B-fragment: lane n16 owns 8 consecutive out cols o=8*n16+nt.
// LDS swizzle: chunk c of row o stored at (o<<4) + ((c + (o>>3)) & 15).
__global__ __launch_bounds__(256) void k_gemm_fused(const short* __restrict__ hb,
                                                    const short* __restrict__ z,
                                                    const short* __restrict__ Bt,
                                                    const float* __restrict__ bias,
                                                    float* __restrict__ out) {
    __shared__ short lds[FEAT * FEAT];                  // 32 KB (one K-chunk of B^T)
    int wave = threadIdx.x >> 6, lane = threadIdx.x & 63;
    int quad = lane >> 4, n16 = lane & 15;
    int base = blockIdx.x * 128 + wave * 32;

    int rowA0 = base + n16;        if (rowA0 >= N_NODES) rowA0 = N_NODES - 1;
    int rowA1 = base + 16 + n16;   if (rowA1 >= N_NODES) rowA1 = N_NODES - 1;

    f32x4 acc[2][8];
#pragma unroll
    for (int mt = 0; mt < 2; ++mt)
#pragma unroll
        for (int nt = 0; nt < 8; ++nt) acc[mt][nt] = (f32x4)0.f;

    float4* l4 = (float4*)lds;
    const bf16x8* bp = (const bf16x8*)lds;

    for (int kc = 0; kc < 5; ++kc) {
        if (kc) __syncthreads();                        // drain reads before restage
        const float4* s4 = (const float4*)(Bt + kc * FEAT * FEAT);
#pragma unroll
        for (int t = 0; t < 8; ++t) {
            int linear = threadIdx.x + t * 256;
            int o = linear >> 4, c = linear & 15;
            l4[(o << 4) + ((c + (o >> 3)) & 15)] = s4[linear];
        }
        __syncthreads();

        const bf16x8* a0p = (kc == 0)
            ? (const bf16x8*)(hb + (size_t)rowA0 * FEAT)
            : (const bf16x8*)(z + (size_t)rowA0 * 512 + (kc - 1) * FEAT);
        const bf16x8* a1p = (kc == 0)
            ? (const bf16x8*)(hb + (size_t)rowA1 * FEAT)
            : (const bf16x8*)(z + (size_t)rowA1 * 512 + (kc - 1) * FEAT);

#pragma unroll
        for (int ks = 0; ks < 4; ++ks) {
            bf16x8 a0 = a0p[ks * 4 + quad];
            bf16x8 a1 = a1p[ks * 4 + quad];
            int sw = (ks * 4 + quad + n16) & 15;
#pragma unroll
            for (int nt = 0; nt < 8; ++nt) {
                int o = n16 * 8 + nt;
                bf16x8 b = bp[(o << 4) + sw];
                acc[0][nt] = __builtin_amdgcn_mfma_f32_16x16x32_bf16(a0, b, acc[0][nt], 0, 0, 0);
                acc[1][nt] = __builtin_amdgcn_mfma_f32_16x16x32_bf16(a1, b, acc[1][nt], 0, 0, 0);
            }
        }
    }

    float bv[8];
#pragma unroll
    for (int nt = 0; nt < 8; ++nt) bv[nt] = bias[n16 * 8 + nt];

#pragma unroll
    for (int mt = 0; mt < 2; ++mt)
#pragma unroll
        for (int reg = 0; reg < 4; ++reg) {
            int node = base + mt * 16 + quad * 4 + reg;
            if (node < N_NODES) {
                float4 fa, fb;
                fa.x = fmaxf(acc[mt][0][reg] + bv[0], 0.f);
                fa.y = fmaxf(acc[mt][1][reg] + bv[1], 0.f);
                fa.z = fmaxf(acc[mt][2][reg] + bv[2], 0.f);
                fa.w = fmaxf(acc[mt][3][reg] + bv[3], 0.f);
                fb.x = fmaxf(acc[mt][4][reg] + bv[4], 0.f);
                fb.y = fmaxf(acc[mt][5][reg] + bv[5], 0.f);
                fb.z = fmaxf(acc[mt][6][reg] + bv[6], 0.f);
                fb.w = fmaxf(acc[mt][7][reg] + bv[7], 0.f);
                float* row = out + (size_t)node * FEAT + n16 * 8;
                *(float4*)row       = fa;
                *(float4*)(row + 4) = fb;
            }
        }
}

// ============================ launch ============================

extern "C" void kernel_launch(void* const* d_in, const int* in_sizes, int n_in,
                              void* d_out, int out_size, void* d_ws, size_t ws_size,
                              hipStream_t stream) {
    const float* h    = (const float*)d_in[0];
    const float* wgt  = (const float*)d_in[1];
    const float* wcmp = (const float*)d_in[2];
    const float* rw   = (const float*)d_in[3];
    const float* bias = (const float*)d_in[4];
    const int*   src  = (const int*)d_in[5];
    const int*   dst  = (const int*)d_in[6];
    const int*   rel  = (const int*)d_in[7];
    float* out = (float*)d_out;

    char* ws = (char*)d_ws;
    short*        hb     = (short*)(ws + 0);
    short*        Bt     = (short*)(ws + 25600000ull);
    short*        z      = (short*)(ws + 25763840ull);
    unsigned int* z_u32  = (unsigned int*)z;
    int*          srcs   = (int*)(ws + 128163840ull);
    float4*       coef   = (float4*)(ws + 130563840ull);
    int*          cnt    = (int*)(ws + 140163840ull);
    int*          offs   = (int*)(ws + 140563840ull);
    int*          cursor = (int*)(ws + 140963968ull);
    int*          status = (int*)(ws + 141363968ull);

    hipLaunchKernelGGL(k_prep,     dim3(PREP_GRID), dim3(256), 0, stream,
                       h, wgt, rw, hb, Bt, cnt, status);
    hipLaunchKernelGGL(k_hist_dst, dim3(NBE),  dim3(256), 0, stream, dst, cnt);
    hipLaunchKernelGGL(k_scan_lb,  dim3(SCAN_TILES), dim3(256), 0, stream,
                       cnt, offs, cursor, status);
    hipLaunchKernelGGL(k_scatter_sorted, dim3(NBE), dim3(256), 0, stream,
                       src, dst, rel, wcmp, cursor, srcs, coef);
    hipLaunchKernelGGL(k_edge_z,   dim3((N_NODES + 3) / 4), dim3(256), 0, stream,
                       offs, srcs, coef, hb, z_u32);
    hipLaunchKernelGGL(k_gemm_fused, dim3((N_NODES + 127) / 128), dim3(256), 0, stream,
                       hb, z, Bt, bias, out);
}

// Round 9
// 276.887 us; speedup vs baseline: 1.2199x; 1.0314x over previous
//
#include <hip/hip_runtime.h>
#include <hip/hip_bf16.h>

#define N_NODES 100000
#define N_EDGES 600000
#define FEAT 128
#define NUM_RELS 8
#define NUM_BASES 4
#define NBE 2344    // ceil(N_EDGES/256)

// grid partition for k_prep
#define PREP_CAST 6250                   // cast_h blocks (6250*256*8 = 12.8M bf16)
#define PREP_BLDB 320                    // build_b blocks (320*256 = 81920 = 5*128*128)
#define PREP_ZERO 392                    // cnt (100000) + scan status (128) zero blocks
#define PREP_GRID (PREP_CAST + PREP_BLDB + PREP_ZERO)

#define SCAN_TILES 98                    // ceil(25000 int4 / 256)

typedef short bf16x8 __attribute__((ext_vector_type(8)));
typedef float f32x4  __attribute__((ext_vector_type(4)));
typedef float f32x2  __attribute__((ext_vector_type(2)));

__device__ inline short f2bf(float x) {
    __hip_bfloat16 b = __float2bfloat16(x);
    return *reinterpret_cast<short*>(&b);
}
__device__ inline float bfbits2f(unsigned int u16) {
    return __int_as_float(u16 << 16);
}

// ws layout (bytes):
//   hb     bf16[N*128]       @ 0            25,600,000
//   Bt     bf16[5*128*128]   @ 25,600,000   163,840   ([kc][o][i'] transposed)
//   z      bf16[N*512]       @ 25,763,840   102,400,000  ([d][b*128+i])
//   packed int[E]            @ 128,163,840  2,400,000 (dst-sorted (src<<3)|rel)
//   cnt    int[N]            @ 130,563,840  400,000
//   offs   int[N+1 pad]      @ 130,963,840  400,128
//   cursor int[N]            @ 131,363,968  400,000
//   status int[128]          @ 131,763,968  512      (lookback-scan tile status)
// total ~131.8 MB

// ---------- k_prep: cast h->bf16 | build B^T | zero cnt+status (grid-partitioned) ----------
__global__ __launch_bounds__(256) void k_prep(const float* __restrict__ h,
                                              const float* __restrict__ weight,
                                              const float* __restrict__ rw,
                                              short* __restrict__ hb,
                                              short* __restrict__ Bt,
                                              int* __restrict__ cnt,
                                              int* __restrict__ status) {
    int b = blockIdx.x;
    if (b < PREP_CAST) {
        int i = b * 256 + threadIdx.x;                 // < 1.6M exactly
        const float4* h4 = (const float4*)h;
        float4 v0 = h4[2 * i], v1 = h4[2 * i + 1];
        union { short s[8]; bf16x8 v; } u;
        u.s[0] = f2bf(v0.x); u.s[1] = f2bf(v0.y); u.s[2] = f2bf(v0.z); u.s[3] = f2bf(v0.w);
        u.s[4] = f2bf(v1.x); u.s[5] = f2bf(v1.y); u.s[6] = f2bf(v1.z); u.s[7] = f2bf(v1.w);
        ((bf16x8*)hb)[i] = u.v;
    } else if (b < PREP_CAST + PREP_BLDB) {
        int idx = (b - PREP_CAST) * 256 + threadIdx.x; // < 81920 exactly
        int kc = idx >> 14;
        int e  = idx & 16383;
        int o  = e >> 7, ip = e & 127;
        float v = (kc == 0) ? rw[ip * FEAT + o]
                            : weight[(kc - 1) * FEAT * FEAT + ip * FEAT + o];
        Bt[idx] = f2bf(v);                             // Bt[kc][o][ip]
    } else {
        int i = (b - PREP_CAST - PREP_BLDB) * 256 + threadIdx.x;
        if (i < N_NODES) cnt[i] = 0;
        else if (i - N_NODES < 128) status[i - N_NODES] = 0;
    }
}

// ---------- dst histogram ----------
__global__ __launch_bounds__(256) void k_hist_dst(const int* __restrict__ dst,
                                                  int* __restrict__ cnt) {
    int i = blockIdx.x * 256 + threadIdx.x;
    if (i < N_EDGES) atomicAdd(&cnt[dst[i]], 1);       // 100K bins, ~6/bin
}

// ---------- decoupled-lookback exclusive scan over cnt[100000] -> offs, cursor ----------
__global__ __launch_bounds__(256) void k_scan_lb(const int* __restrict__ cnt,
                                                 int* __restrict__ offs,
                                                 int* __restrict__ cursor,
                                                 int* __restrict__ status) {
    __shared__ int wsum[4];
    __shared__ int bcast;
    int bid = blockIdx.x;
    int lane = threadIdx.x & 63, wid = threadIdx.x >> 6;
    const int N4 = N_NODES / 4;                        // 25000
    int i4 = bid * 256 + threadIdx.x;

    const int4* cnt4 = (const int4*)cnt;
    int4 v = (i4 < N4) ? cnt4[i4] : make_int4(0, 0, 0, 0);
    int s = v.x + v.y + v.z + v.w;
    int incl = s;
#pragma unroll
    for (int d = 1; d < 64; d <<= 1) {
        int t = __shfl_up(incl, d);
        if (lane >= d) incl += t;
    }
    if (lane == 63) wsum[wid] = incl;
    __syncthreads();
    if (threadIdx.x == 0) {
        int a = 0;
#pragma unroll
        for (int w = 0; w < 4; ++w) { int x = wsum[w]; wsum[w] = a; a += x; }
        int total = a;
        __hip_atomic_store(&status[bid], (total << 2) | 1,
                           __ATOMIC_RELEASE, __HIP_MEMORY_SCOPE_AGENT);
        int excl = 0;
        for (int t = bid - 1; t >= 0; ) {
            int st = __hip_atomic_load(&status[t],
                                       __ATOMIC_ACQUIRE, __HIP_MEMORY_SCOPE_AGENT);
            if ((st & 3) == 0) { __builtin_amdgcn_s_sleep(1); continue; }
            excl += st >> 2;
            if ((st & 3) == 2) break;
            --t;
        }
        __hip_atomic_store(&status[bid], ((excl + total) << 2) | 2,
                           __ATOMIC_RELEASE, __HIP_MEMORY_SCOPE_AGENT);
        bcast = excl;
        if (bid == SCAN_TILES - 1) offs[N_NODES] = excl + total;   // == N_EDGES
    }
    __syncthreads();
    int base = bcast + wsum[wid] + incl - s;
    if (i4 < N4) {
        int4 ex;
        ex.x = base;
        ex.y = base + v.x;
        ex.z = base + v.x + v.y;
        ex.w = base + v.x + v.y + v.z;
        ((int4*)offs)[i4]   = ex;
        ((int4*)cursor)[i4] = ex;
    }
}

// ---------- scatter: dst-sorted packed (src<<3)|rel — one 4B word per edge ----------
__global__ __launch_bounds__(256) void k_scatter_sorted(const int* __restrict__ src,
                                                        const int* __restrict__ dst,
                                                        const int* __restrict__ rel,
                                                        int* __restrict__ cursor,
                                                        int* __restrict__ packed) {
    int e = blockIdx.x * 256 + threadIdx.x;
    if (e < N_EDGES) {
        int p = atomicAdd(&cursor[dst[e]], 1);         // ~6-way contention
        packed[p] = (src[e] << 3) | rel[e];
    }
}

// ---------- edge phase: z[d][b][:] = sum_{e->d} w_comp[rel,b] * h[src]  (1 wave/dst) ----------
// Cooperative edge loading: lane j preloads packed[s+j]; per-edge readlane broadcast
// + LDS w_comp lookup. One VMEM gather per edge, pk-FMA accumulation.
__global__ __launch_bounds__(256) void k_edge_z(const int* __restrict__ offs,
                                                const int* __restrict__ packed,
                                                const float* __restrict__ wc,
                                                const short* __restrict__ hb,
                                                unsigned int* __restrict__ z_u32) {
    __shared__ float4 wcs[NUM_RELS];
    if (threadIdx.x < NUM_RELS) {
        int r = threadIdx.x * NUM_BASES;
        wcs[threadIdx.x] = make_float4(wc[r], wc[r + 1], wc[r + 2], wc[r + 3]);
    }
    __syncthreads();

    int wid = threadIdx.x >> 6, lane = threadIdx.x & 63;
    int d = blockIdx.x * 4 + wid;
    if (d >= N_NODES) return;
    int s = offs[d], e = offs[d + 1];

    f32x2 z2[4] = {(f32x2)0.f, (f32x2)0.f, (f32x2)0.f, (f32x2)0.f};

    for (int base = s; base < e; base += 64) {
        int rem = e - base;
        int m = rem < 64 ? rem : 64;
        int pk = (lane < m) ? packed[base + lane] : 0;  // coalesced group load
        int j = 0;
        for (; j + 1 < m; j += 2) {
            int p0 = __builtin_amdgcn_readlane(pk, j);
            int p1 = __builtin_amdgcn_readlane(pk, j + 1);
            int s0 = p0 >> 3, s1 = p1 >> 3;
            float4 c0 = wcs[p0 & 7];                    // LDS broadcast
            float4 c1 = wcs[p1 & 7];
            unsigned int v0 = ((const unsigned int*)(hb + (size_t)s0 * FEAT))[lane];
            unsigned int v1 = ((const unsigned int*)(hb + (size_t)s1 * FEAT))[lane];
            f32x2 h0; h0.x = bfbits2f(v0 & 0xffffu); h0.y = bfbits2f(v0 >> 16);
            f32x2 h1; h1.x = bfbits2f(v1 & 0xffffu); h1.y = bfbits2f(v1 >> 16);
            f32x2 cc;
            cc = c0.x; z2[0] += cc * h0;
            cc = c0.y; z2[1] += cc * h0;
            cc = c0.z; z2[2] += cc * h0;
            cc = c0.w; z2[3] += cc * h0;
            cc = c1.x; z2[0] += cc * h1;
            cc = c1.y; z2[1] += cc * h1;
            cc = c1.z; z2[2] += cc * h1;
            cc = c1.w; z2[3] += cc * h1;
        }
        if (j < m) {
            int p0 = __builtin_amdgcn_readlane(pk, j);
            int s0 = p0 >> 3;
            float4 c0 = wcs[p0 & 7];
            unsigned int v0 = ((const unsigned int*)(hb + (size_t)s0 * FEAT))[lane];
            f32x2 h0; h0.x = bfbits2f(v0 & 0xffffu); h0.y = bfbits2f(v0 >> 16);
            f32x2 cc;
            cc = c0.x; z2[0] += cc * h0;
            cc = c0.y; z2[1] += cc * h0;
            cc = c0.z; z2[2] += cc * h0;
            cc = c0.w; z2[3] += cc * h0;
        }
    }

    unsigned int* row = z_u32 + (size_t)d * 256;       // 512 bf16 = 256 u32
#pragma unroll
    for (int b = 0; b < 4; ++b) {
        unsigned int lo = ((unsigned int)(unsigned short)f2bf(z2[b].x));
        unsigned int hi = ((unsigned int)(unsigned short)f2bf(z2[b].y)) << 16;
        row[b * 64 + lane] = lo | hi;                  // coalesced 256B per b
    }
}

// ---------- fused GEMM: out = relu([hb | z] @ Bt + bias), K=640 ----------
// B-fragment: lane n16 owns 8 consecutive out cols o=8*n16+nt.
// LDS swizzle: chunk c of row o stored at (o<<4) + ((c + (o>>3)) & 15).
__global__ __launch_bounds__(256) void k_gemm_fused(const short* __restrict__ hb,
                                                    const short* __restrict__ z,
                                                    const short* __restrict__ Bt,
                                                    const float* __restrict__ bias,
                                                    float* __restrict__ out) {
    __shared__ short lds[FEAT * FEAT];                  // 32 KB (one K-chunk of B^T)
    int wave = threadIdx.x >> 6, lane = threadIdx.x & 63;
    int quad = lane >> 4, n16 = lane & 15;
    int base = blockIdx.x * 128 + wave * 32;

    int rowA0 = base + n16;        if (rowA0 >= N_NODES) rowA0 = N_NODES - 1;
    int rowA1 = base + 16 + n16;   if (rowA1 >= N_NODES) rowA1 = N_NODES - 1;

    f32x4 acc[2][8];
#pragma unroll
    for (int mt = 0; mt < 2; ++mt)
#pragma unroll
        for (int nt = 0; nt < 8; ++nt) acc[mt][nt] = (f32x4)0.f;

    float4* l4 = (float4*)lds;
    const bf16x8* bp = (const bf16x8*)lds;

    for (int kc = 0; kc < 5; ++kc) {
        if (kc) __syncthreads();                        // drain reads before restage
        const float4* s4 = (const float4*)(Bt + kc * FEAT * FEAT);
#pragma unroll
        for (int t = 0; t < 8; ++t) {
            int linear = threadIdx.x + t * 256;
            int o = linear >> 4, c = linear & 15;
            l4[(o << 4) + ((c + (o >> 3)) & 15)] = s4[linear];
        }
        __syncthreads();

        const bf16x8* a0p = (kc == 0)
            ? (const bf16x8*)(hb + (size_t)rowA0 * FEAT)
            : (const bf16x8*)(z + (size_t)rowA0 * 512 + (kc - 1) * FEAT);
        const bf16x8* a1p = (kc == 0)
            ? (const bf16x8*)(hb + (size_t)rowA1 * FEAT)
            : (const bf16x8*)(z + (size_t)rowA1 * 512 + (kc - 1) * FEAT);

#pragma unroll
        for (int ks = 0; ks < 4; ++ks) {
            bf16x8 a0 = a0p[ks * 4 + quad];
            bf16x8 a1 = a1p[ks * 4 + quad];
            int sw = (ks * 4 + quad + n16) & 15;
#pragma unroll
            for (int nt = 0; nt < 8; ++nt) {
                int o = n16 * 8 + nt;
                bf16x8 b = bp[(o << 4) + sw];
                acc[0][nt] = __builtin_amdgcn_mfma_f32_16x16x32_bf16(a0, b, acc[0][nt], 0, 0, 0);
                acc[1][nt] = __builtin_amdgcn_mfma_f32_16x16x32_bf16(a1, b, acc[1][nt], 0, 0, 0);
            }
        }
    }

    float bv[8];
#pragma unroll
    for (int nt = 0; nt < 8; ++nt) bv[nt] = bias[n16 * 8 + nt];

#pragma unroll
    for (int mt = 0; mt < 2; ++mt)
#pragma unroll
        for (int reg = 0; reg < 4; ++reg) {
            int node = base + mt * 16 + quad * 4 + reg;
            if (node < N_NODES) {
                float4 fa, fb;
                fa.x = fmaxf(acc[mt][0][reg] + bv[0], 0.f);
                fa.y = fmaxf(acc[mt][1][reg] + bv[1], 0.f);
                fa.z = fmaxf(acc[mt][2][reg] + bv[2], 0.f);
                fa.w = fmaxf(acc[mt][3][reg] + bv[3], 0.f);
                fb.x = fmaxf(acc[mt][4][reg] + bv[4], 0.f);
                fb.y = fmaxf(acc[mt][5][reg] + bv[5], 0.f);
                fb.z = fmaxf(acc[mt][6][reg] + bv[6], 0.f);
                fb.w = fmaxf(acc[mt][7][reg] + bv[7], 0.f);
                float* row = out + (size_t)node * FEAT + n16 * 8;
                *(float4*)row       = fa;
                *(float4*)(row + 4) = fb;
            }
        }
}

// ============================ launch ============================

extern "C" void kernel_launch(void* const* d_in, const int* in_sizes, int n_in,
                              void* d_out, int out_size, void* d_ws, size_t ws_size,
                              hipStream_t stream) {
    const float* h    = (const float*)d_in[0];
    const float* wgt  = (const float*)d_in[1];
    const float* wcmp = (const float*)d_in[2];
    const float* rw   = (const float*)d_in[3];
    const float* bias = (const float*)d_in[4];
    const int*   src  = (const int*)d_in[5];
    const int*   dst  = (const int*)d_in[6];
    const int*   rel  = (const int*)d_in[7];
    float* out = (float*)d_out;

    char* ws = (char*)d_ws;
    short*        hb     = (short*)(ws + 0);
    short*        Bt     = (short*)(ws + 25600000ull);
    short*        z      = (short*)(ws + 25763840ull);
    unsigned int* z_u32  = (unsigned int*)z;
    int*          packed = (int*)(ws + 128163840ull);
    int*          cnt    = (int*)(ws + 130563840ull);
    int*          offs   = (int*)(ws + 130963840ull);
    int*          cursor = (int*)(ws + 131363968ull);
    int*          status = (int*)(ws + 131763968ull);

    hipLaunchKernelGGL(k_prep,     dim3(PREP_GRID), dim3(256), 0, stream,
                       h, wgt, rw, hb, Bt, cnt, status);
    hipLaunchKernelGGL(k_hist_dst, dim3(NBE),  dim3(256), 0, stream, dst, cnt);
    hipLaunchKernelGGL(k_scan_lb,  dim3(SCAN_TILES), dim3(256), 0, stream,
                       cnt, offs, cursor, status);
    hipLaunchKernelGGL(k_scatter_sorted, dim3(NBE), dim3(256), 0, stream,
                       src, dst, rel, cursor, packed);
    hipLaunchKernelGGL(k_edge_z,   dim3((N_NODES + 3) / 4), dim3(256), 0, stream,
                       offs, packed, wcmp, hb, z_u32);
    hipLaunchKernelGGL(k_gemm_fused, dim3((N_NODES + 127) / 128), dim3(256), 0, stream,
                       hb, z, Bt, bias, out);
}